// Round 5
// baseline (246.148 us; speedup 1.0000x reference)
//
#include <hip/hip_runtime.h>

// VGAE GCN encoder: radix-binned CSR build (staged, coalesced) + XCD-pinned
// 8-way feature-chunked CSR gather aggregation + register-pipelined fp16 MFMA
// GEMMs.  n=100000, f=256, hid=128, dout=64, E=1.6M (read from in_sizes).
//
// Algebra (norm-folded): hs = (X@W1)*dis (fp16);
//   agg1: acc_i = hs_i + sum_{s in N(i)} hs_s ; h1s_i = relu(dis_i*acc_i + b1)*dis_i
//   agg2: agg2_i = dis_i*(h1s_i + sum h1s_s)  ; out = agg2 @ [Wmu|Wvar] + bias
//
// Round-11 single-variable test: r3 (8-way chunk, 150us) minus NT col loads.
// Forensics: both slow rounds (r2 188us, r3 150us) used nontemporal col loads;
// fast rounds (r1 60us, r4 ~52us) used plain. Consecutive nodes have adjacent
// CSR ranges -> plain col loads get ~17 reads/line from L1/L2; NT bypasses
// caches -> ~12.8M individual fabric round-trips (invisible in FETCH_SIZE
// because they hit Infinity Cache, not HBM). 8-way chunking itself is the
// only config whose per-XCD slice (3.2MB) FULLY fits the 4MB L2 (r2 proved:
// FETCH 188->44MB). chunk = blockIdx.x & 7 -> round-robin XCD pinning.
// NOTE (r6): per-bucket LDS-atomic aggregation regressed 20x.
// NOTE (r7): deeper per-lane gather pipelining alone is exhausted (+6%).
// NOTE (r2): per-node-chunk shfl reduce (800k x 24 instr) regressed.

#define HID 128
#define DOUT 64
#define NB_SHIFT 8          // 256 nodes per bucket
#define CHUNK 8192          // edges per binning block
#define MAXNB 400           // max buckets (n <= 102400)

typedef _Float16 half_t;
typedef half_t f16x4 __attribute__((ext_vector_type(4)));
typedef half_t f16x8 __attribute__((ext_vector_type(8)));
typedef float  f32x4 __attribute__((ext_vector_type(4)));

// ==================== CSR build ====================

__global__ __launch_bounds__(256) void bincount_kernel(const int* __restrict__ dst,
                                                       int* __restrict__ counts,
                                                       int E, int nblocks, int NB) {
    __shared__ int hist[MAXNB];
    const int b = blockIdx.x;
    for (int t = threadIdx.x; t < NB; t += 256) hist[t] = 0;
    __syncthreads();
    const int beg = b * CHUNK;
    const int end = min(E, beg + CHUNK);
    for (int e = beg + threadIdx.x; e < end; e += 256)
        atomicAdd(&hist[dst[e] >> NB_SHIFT], 1);
    __syncthreads();
    for (int t = threadIdx.x; t < NB; t += 256)
        counts[t * nblocks + b] = hist[t];
}

__global__ __launch_bounds__(256) void scan1_kernel(const int* __restrict__ in,
                                                    int* __restrict__ out,
                                                    int* __restrict__ bsum, int n) {
    __shared__ int s[256];
    int b = blockIdx.x, t = threadIdx.x;
    int base = b * 1024 + t * 4;
    int v0 = 0, v1 = 0, v2 = 0, v3 = 0;
    if (base + 0 < n) v0 = in[base + 0];
    if (base + 1 < n) v1 = in[base + 1];
    if (base + 2 < n) v2 = in[base + 2];
    if (base + 3 < n) v3 = in[base + 3];
    int tsum = v0 + v1 + v2 + v3;
    s[t] = tsum;
    __syncthreads();
    for (int off = 1; off < 256; off <<= 1) {
        int x = (t >= off) ? s[t - off] : 0;
        __syncthreads();
        s[t] += x;
        __syncthreads();
    }
    int excl = s[t] - tsum;
    if (base + 0 < n) out[base + 0] = excl;
    if (base + 1 < n) out[base + 1] = excl + v0;
    if (base + 2 < n) out[base + 2] = excl + v0 + v1;
    if (base + 3 < n) out[base + 3] = excl + v0 + v1 + v2;
    if (t == 255) bsum[b] = s[255];
}

// parallel single-block scan of block sums (nb <= 1024)
__global__ __launch_bounds__(1024) void scan2_kernel(int* __restrict__ bsum, int nb) {
    __shared__ int s[1024];
    int t = threadIdx.x;
    int v = (t < nb) ? bsum[t] : 0;
    s[t] = v;
    __syncthreads();
    for (int off = 1; off < 1024; off <<= 1) {
        int x = (t >= off) ? s[t - off] : 0;
        __syncthreads();
        s[t] += x;
        __syncthreads();
    }
    if (t < nb) bsum[t] = s[t] - v;   // exclusive
}

__global__ void scan3_kernel(int* __restrict__ out, const int* __restrict__ bsum, int n) {
    int i = blockIdx.x * blockDim.x + threadIdx.x;
    if (i < n) out[i] += bsum[i >> 10];
}

// LDS-staged binscatter: counting-sort the 8192-edge chunk in LDS, then write
// each (bucket,chunk) segment contiguously -> write amplification ~1.
__global__ __launch_bounds__(1024) void binscatter_kernel(const int* __restrict__ src,
                                                          const int* __restrict__ dst,
                                                          const int* __restrict__ offsets,
                                                          int2* __restrict__ binned,
                                                          int E, int nblocks, int NB) {
    __shared__ int  lhist[1024];
    __shared__ int  lbase[1024];
    __shared__ int  cur[1024];
    __shared__ int  goff[MAXNB];
    __shared__ int2 staged[CHUNK];
    const int b = blockIdx.x, t = threadIdx.x;
    const int beg = b * CHUNK;
    const int end = min(E, beg + CHUNK);
    const int ne  = end - beg;

    lhist[t] = 0;
    for (int k = t; k < NB; k += 1024) goff[k] = offsets[k * nblocks + b];
    __syncthreads();

    // pass 1: histogram (edges kept in registers)
    int2 regs[8];
    #pragma unroll
    for (int j = 0; j < 8; j++) {
        int e = beg + t + j * 1024;
        if (e < end) {
            regs[j] = make_int2(src[e], dst[e]);
            atomicAdd(&lhist[regs[j].y >> NB_SHIFT], 1);
        }
    }
    __syncthreads();

    // inclusive scan of lhist -> exclusive bases
    int hv = lhist[t];
    for (int off = 1; off < 1024; off <<= 1) {
        int x = (t >= off) ? lhist[t - off] : 0;
        __syncthreads();
        lhist[t] += x;
        __syncthreads();
    }
    lbase[t] = lhist[t] - hv;
    cur[t]   = lhist[t] - hv;
    __syncthreads();

    // pass 2: place into LDS staging at local rank
    #pragma unroll
    for (int j = 0; j < 8; j++) {
        int e = beg + t + j * 1024;
        if (e < end) {
            int pos = atomicAdd(&cur[regs[j].y >> NB_SHIFT], 1);
            staged[pos] = regs[j];
        }
    }
    __syncthreads();

    // pass 3: linear write-out; consecutive t -> consecutive global addrs per segment
    #pragma unroll
    for (int j = 0; j < 8; j++) {
        int tt = t + j * 1024;
        if (tt < ne) {
            int2 sd = staged[tt];
            int bkt = sd.y >> NB_SHIFT;
            binned[goff[bkt] + (tt - lbase[bkt])] = sd;
        }
    }
}

// one WG per 256-node bucket: local degree hist -> local scan -> dis/rowptr_end
// (coalesced) -> place col within the bucket's 16KB window.
__global__ __launch_bounds__(256) void csrbuild_kernel(const int2* __restrict__ binned,
                                                       const int* __restrict__ offsets,
                                                       int* __restrict__ rowptr_end,
                                                       int* __restrict__ colA,
                                                       float* __restrict__ dis,
                                                       int E, int nblocks, int NB, int n) {
    __shared__ int deg[256];
    __shared__ int sc[256];
    __shared__ int cur[256];
    const int b = blockIdx.x;
    const int t = threadIdx.x;
    const int base = offsets[b * nblocks];
    const int bend = (b + 1 < NB) ? offsets[(b + 1) * nblocks] : E;

    deg[t] = 0;
    __syncthreads();
    for (int e = base + t; e < bend; e += 256)
        atomicAdd(&deg[binned[e].y & 255], 1);
    __syncthreads();

    int v = deg[t];
    sc[t] = v;
    __syncthreads();
    for (int off = 1; off < 256; off <<= 1) {
        int x = (t >= off) ? sc[t - off] : 0;
        __syncthreads();
        sc[t] += x;
        __syncthreads();
    }
    int incl = sc[t];
    int node = (b << NB_SHIFT) + t;
    if (node < n) {
        rowptr_end[node] = base + incl;
        dis[node] = rsqrtf((float)v + 1.0f);
    }
    cur[t] = base + incl - v;
    __syncthreads();

    for (int e = base + t; e < bend; e += 256) {
        int2 sd = binned[e];
        int pos = atomicAdd(&cur[sd.y & 255], 1);
        colA[pos] = sd.x;
    }
}

// ==================== weight prep ====================
__global__ void w1t_kernel(const float* __restrict__ W1, half_t* __restrict__ W1T) {
    int i = blockIdx.x * blockDim.x + threadIdx.x;   // 256*128
    int k = i >> 7, nn = i & 127;
    W1T[nn * 256 + k] = (half_t)W1[i];
}
__global__ void wcatt_kernel(const float* __restrict__ Wmu, const float* __restrict__ Wvar,
                             half_t* __restrict__ WcatT) {
    int i = blockIdx.x * blockDim.x + threadIdx.x;   // 128*128
    int k = i >> 7, nn = i & 127;
    float v = (nn < DOUT) ? Wmu[k * DOUT + nn] : Wvar[k * DOUT + (nn - DOUT)];
    WcatT[nn * 128 + k] = (half_t)v;
}

// ==================== MFMA GEMM1 (register-prefetch pipelined) ====================
// hs[chunk][M][16](fp16) = (A[M,256](fp32) @ W1T^T) * dis[row], chunk-major out.
__global__ __launch_bounds__(256) void gemm1_mfma(const float* __restrict__ A,
                                                  const half_t* __restrict__ BT,
                                                  const float* __restrict__ dis,
                                                  half_t* __restrict__ C, int M) {
    __shared__ half_t As[64][72];
    __shared__ half_t Bs[128][72];
    const int tid = threadIdx.x;
    const int block_row = blockIdx.x * 64;
    const int wave = tid >> 6, lane = tid & 63;
    const int wm = (wave & 1) * 32, wn = (wave >> 1) * 64;
    const int l16 = lane & 15, quad = lane >> 4;

    f32x4 acc[2][4] = {};
    float4 pa[4];
    f16x8  pb[4];

    #pragma unroll
    for (int i = 0; i < 4; i++) {
        int idx = tid + i * 256;
        int r = idx >> 4, c = idx & 15;
        int row = block_row + r; row = row < M ? row : M - 1;
        pa[i] = ((const float4*)(A + (size_t)row * 256))[c];
    }
    #pragma unroll
    for (int i = 0; i < 4; i++) {
        int idx = tid + i * 256;
        int nr = idx >> 3, kc = idx & 7;
        pb[i] = *(const f16x8*)(BT + (size_t)nr * 256 + kc * 8);
    }

    for (int k0 = 0; k0 < 256; k0 += 64) {
        #pragma unroll
        for (int i = 0; i < 4; i++) {
            int idx = tid + i * 256;
            int r = idx >> 4, c = idx & 15;
            f16x4 hv = { (half_t)pa[i].x, (half_t)pa[i].y, (half_t)pa[i].z, (half_t)pa[i].w };
            *(f16x4*)(&As[r][c * 4]) = hv;
        }
        #pragma unroll
        for (int i = 0; i < 4; i++) {
            int idx = tid + i * 256;
            int nr = idx >> 3, kc = idx & 7;
            *(f16x8*)(&Bs[nr][kc * 8]) = pb[i];
        }
        __syncthreads();

        if (k0 < 192) {
            #pragma unroll
            for (int i = 0; i < 4; i++) {
                int idx = tid + i * 256;
                int r = idx >> 4, c = idx & 15;
                int row = block_row + r; row = row < M ? row : M - 1;
                pa[i] = ((const float4*)(A + (size_t)row * 256 + k0 + 64))[c];
            }
            #pragma unroll
            for (int i = 0; i < 4; i++) {
                int idx = tid + i * 256;
                int nr = idx >> 3, kc = idx & 7;
                pb[i] = *(const f16x8*)(BT + (size_t)nr * 256 + k0 + 64 + kc * 8);
            }
        }

        #pragma unroll
        for (int ks = 0; ks < 2; ks++) {
            f16x8 af[2], bf[4];
            #pragma unroll
            for (int mt = 0; mt < 2; mt++)
                af[mt] = *(const f16x8*)(&As[wm + mt * 16 + l16][ks * 32 + quad * 8]);
            #pragma unroll
            for (int nt = 0; nt < 4; nt++)
                bf[nt] = *(const f16x8*)(&Bs[wn + nt * 16 + l16][ks * 32 + quad * 8]);
            #pragma unroll
            for (int mt = 0; mt < 2; mt++)
                #pragma unroll
                for (int nt = 0; nt < 4; nt++)
                    acc[mt][nt] = __builtin_amdgcn_mfma_f32_16x16x32_f16(af[mt], bf[nt], acc[mt][nt], 0, 0, 0);
        }
        __syncthreads();
    }

    #pragma unroll
    for (int mt = 0; mt < 2; mt++) {
        #pragma unroll
        for (int r = 0; r < 4; r++) {
            int row = block_row + wm + mt * 16 + quad * 4 + r;
            if (row < M) {
                float d = dis[row];
                #pragma unroll
                for (int nt = 0; nt < 4; nt++) {
                    int cchunk = (wn >> 4) + nt;           // feature chunk (l16 spans it)
                    C[((size_t)cchunk * M + row) * 16 + l16] = (half_t)(acc[mt][nt][r] * d);
                }
            }
        }
    }
}

// ==================== MFMA GEMM2 (pipelined; chunk-major A) ====================
__global__ __launch_bounds__(256) void gemm2_mfma(const half_t* __restrict__ A,
                                                  const half_t* __restrict__ BT,
                                                  const float* __restrict__ bmu,
                                                  const float* __restrict__ bvar,
                                                  float* __restrict__ out_mu,
                                                  float* __restrict__ out_sig, int M) {
    __shared__ half_t As[64][72];
    __shared__ half_t Bs[128][72];
    const int tid = threadIdx.x;
    const int block_row = blockIdx.x * 64;
    const int wave = tid >> 6, lane = tid & 63;
    const int wm = (wave & 1) * 32, wn = (wave >> 1) * 64;
    const int l16 = lane & 15, quad = lane >> 4;

    f32x4 acc[2][4] = {};
    f16x8 pa[2], pb[4];

    // A[chunk][M][16]: feature f = kbase + kc*8 -> chunk = (kbase>>4)+(kc>>1),
    // in-chunk offset = (kc&1)*8.
    #pragma unroll
    for (int i = 0; i < 2; i++) {
        int idx = tid + i * 256;
        int r = idx >> 3, kc = idx & 7;
        int row = block_row + r; row = row < M ? row : M - 1;
        pa[i] = *(const f16x8*)(A + ((size_t)(kc >> 1) * M + row) * 16 + (kc & 1) * 8);
    }
    #pragma unroll
    for (int i = 0; i < 4; i++) {
        int idx = tid + i * 256;
        int nr = idx >> 3, kc = idx & 7;
        pb[i] = *(const f16x8*)(BT + (size_t)nr * 128 + kc * 8);
    }

    for (int k0 = 0; k0 < 128; k0 += 64) {
        #pragma unroll
        for (int i = 0; i < 2; i++) {
            int idx = tid + i * 256;
            int r = idx >> 3, kc = idx & 7;
            *(f16x8*)(&As[r][kc * 8]) = pa[i];
        }
        #pragma unroll
        for (int i = 0; i < 4; i++) {
            int idx = tid + i * 256;
            int nr = idx >> 3, kc = idx & 7;
            *(f16x8*)(&Bs[nr][kc * 8]) = pb[i];
        }
        __syncthreads();

        if (k0 < 64) {
            #pragma unroll
            for (int i = 0; i < 2; i++) {
                int idx = tid + i * 256;
                int r = idx >> 3, kc = idx & 7;
                int row = block_row + r; row = row < M ? row : M - 1;
                pa[i] = *(const f16x8*)(A + ((size_t)(4 + (kc >> 1)) * M + row) * 16 + (kc & 1) * 8);
            }
            #pragma unroll
            for (int i = 0; i < 4; i++) {
                int idx = tid + i * 256;
                int nr = idx >> 3, kc = idx & 7;
                pb[i] = *(const f16x8*)(BT + (size_t)nr * 128 + 64 + kc * 8);
            }
        }

        #pragma unroll
        for (int ks = 0; ks < 2; ks++) {
            f16x8 af[2], bf[4];
            #pragma unroll
            for (int mt = 0; mt < 2; mt++)
                af[mt] = *(const f16x8*)(&As[wm + mt * 16 + l16][ks * 32 + quad * 8]);
            #pragma unroll
            for (int nt = 0; nt < 4; nt++)
                bf[nt] = *(const f16x8*)(&Bs[wn + nt * 16 + l16][ks * 32 + quad * 8]);
            #pragma unroll
            for (int mt = 0; mt < 2; mt++)
                #pragma unroll
                for (int nt = 0; nt < 4; nt++)
                    acc[mt][nt] = __builtin_amdgcn_mfma_f32_16x16x32_f16(af[mt], bf[nt], acc[mt][nt], 0, 0, 0);
        }
        __syncthreads();
    }

    float bias[4];
    int cols[4];
    #pragma unroll
    for (int nt = 0; nt < 4; nt++) {
        int col = wn + nt * 16 + l16;
        cols[nt] = col;
        bias[nt] = (col < DOUT) ? bmu[col] : bvar[col - DOUT];
    }

    #pragma unroll
    for (int mt = 0; mt < 2; mt++) {
        #pragma unroll
        for (int r = 0; r < 4; r++) {
            int row = block_row + wm + mt * 16 + quad * 4 + r;
            if (row < M) {
                #pragma unroll
                for (int nt = 0; nt < 4; nt++) {
                    int col = cols[nt];
                    float v = acc[mt][nt][r] + bias[nt];
                    if (col < DOUT) out_mu[(size_t)row * DOUT + col] = v;
                    else            out_sig[(size_t)row * DOUT + (col - DOUT)] = v;
                }
            }
        }
    }
}

// ==================== aggregation (8-way XCD-pinned chunks, plain col) ====================
// hin/hout chunk-major [8][n][16] fp16.  chunk = blockIdx.x & 7 -> XCD pin;
// each XCD's 3.2MB slice is fully L2-resident (r2: FETCH 188->44MB).
// 4 lanes own one node's 16-feat slice (fq = lane&3), 16 nodes per wave.
// Per node: 8-deep col batch + 8-deep gather batch, register accumulate.
// col loads are PLAIN CACHED (the r2/r3 NT loads were the regression: ~12.8M
// uncached 4B fabric round-trips; plain gets ~17 reads/line via L1/L2).
// v_fma_mix_f32: acc(f32) += f16_half(S0)*S1(f32); flag doubles as tail mask.
__device__ __forceinline__ void acc_mix(float& a0, float& a1, float& a2, float& a3,
                                        f16x4 v, float fl) {
    union { f16x4 h; int i[2]; } u; u.h = v;
    asm("v_fma_mix_f32 %0, %1, %2, %0 op_sel_hi:[1,0,0]"
        : "+v"(a0) : "v"(u.i[0]), "v"(fl));
    asm("v_fma_mix_f32 %0, %1, %2, %0 op_sel:[1,0,0] op_sel_hi:[1,0,0]"
        : "+v"(a1) : "v"(u.i[0]), "v"(fl));
    asm("v_fma_mix_f32 %0, %1, %2, %0 op_sel_hi:[1,0,0]"
        : "+v"(a2) : "v"(u.i[1]), "v"(fl));
    asm("v_fma_mix_f32 %0, %1, %2, %0 op_sel:[1,0,0] op_sel_hi:[1,0,0]"
        : "+v"(a3) : "v"(u.i[1]), "v"(fl));
}

template <bool LAYER1>
__global__ __launch_bounds__(256) void agg_kernel(const int* __restrict__ rowptr_end,
                                                  const int* __restrict__ col,
                                                  const float* __restrict__ dis,
                                                  const half_t* __restrict__ hin,
                                                  half_t* __restrict__ hout,
                                                  const float* __restrict__ bias, int n) {
    const int chunk = blockIdx.x & 7;                       // -> XCD chunk&7
    const int node  = (blockIdx.x >> 3) * 64 + (threadIdx.x >> 2);
    if (node >= n) return;
    const int fq = threadIdx.x & 3;    // feature quad (4 fp16) within 16-slice

    const f16x4* hc = (const f16x4*)(hin + (size_t)chunk * n * 16);

    int beg = (node == 0) ? 0 : rowptr_end[node - 1];   // plain cached loads
    int end = rowptr_end[node];

    float one = 1.0f;
    float ax = 0.f, ay = 0.f, az = 0.f, aw = 0.f;
    acc_mix(ax, ay, az, aw, hc[node * 4 + fq], one);    // self term

    int deg = end - beg;
    if (deg > 0) {
        const int last = end - 1;
        int c[8];
        #pragma unroll
        for (int j = 0; j < 8; j++)
            c[j] = col[min(beg + j, last)];             // plain cached

        int ng = (deg + 7) >> 3;
        int e = beg;
        for (int g = 0; g < ng; g++) {
            // issue the 8 long-latency gathers first (L2-resident slice)
            f16x4 v[8];
            #pragma unroll
            for (int j = 0; j < 8; j++) v[j] = hc[c[j] * 4 + fq];

            int enext = e + 8;
            if (g + 1 < ng) {
                // prefetch next col batch while gathers are in flight
                #pragma unroll
                for (int j = 0; j < 8; j++)
                    c[j] = col[min(enext + j, last)];   // plain cached
                #pragma unroll
                for (int j = 0; j < 8; j++) acc_mix(ax, ay, az, aw, v[j], one);
            } else {
                int rem = end - e;   // 1..8 valid edges in the final group
                #pragma unroll
                for (int j = 0; j < 8; j++) {
                    float fl = (j < rem) ? 1.0f : 0.0f;
                    acc_mix(ax, ay, az, aw, v[j], fl);
                }
            }
            e = enext;
        }
    }

    float di = dis[node];
    if (LAYER1) {
        const float4 b = ((const float4*)bias)[chunk * 4 + fq];
        ax = ax * di + b.x; ay = ay * di + b.y; az = az * di + b.z; aw = aw * di + b.w;
        ax = (ax > 0.f ? ax : 0.f) * di;
        ay = (ay > 0.f ? ay : 0.f) * di;
        az = (az > 0.f ? az : 0.f) * di;
        aw = (aw > 0.f ? aw : 0.f) * di;
    } else {
        ax *= di; ay *= di; az *= di; aw *= di;
    }
    f16x4 o = { (half_t)ax, (half_t)ay, (half_t)az, (half_t)aw };
    ((f16x4*)(hout + (size_t)chunk * n * 16))[node * 4 + fq] = o;
}

extern "C" void kernel_launch(void* const* d_in, const int* in_sizes, int n_in,
                              void* d_out, int out_size, void* d_ws, size_t ws_size,
                              hipStream_t stream) {
    const float* x    = (const float*)d_in[0];
    const int*   ei   = (const int*)d_in[1];
    const float* W1   = (const float*)d_in[2];
    const float* b1   = (const float*)d_in[3];
    const float* Wmu  = (const float*)d_in[4];
    const float* bmu  = (const float*)d_in[5];
    const float* Wvar = (const float*)d_in[6];
    const float* bvar = (const float*)d_in[7];

    const int n = in_sizes[0] / 256;     // 100000
    const int E = in_sizes[1] / 2;       // 1600000
    const int* src = ei;
    const int* dst = ei + E;

    const int NB      = (n + 255) >> NB_SHIFT;       // 391
    const int nblocks = (E + CHUNK - 1) / CHUNK;     // 196
    const int flat    = NB * nblocks;
    const int nb_scan = (flat + 1023) / 1024;        // 75 (<= 1024)

    char* ws = (char*)d_ws;
    size_t off = 0;
    auto alloc = [&](size_t bytes) { void* p = ws + off; off = (off + bytes + 255) & ~(size_t)255; return p; };
    float*  dis     = (float*) alloc((size_t)n * 4);
    int*    rowptr  = (int*)   alloc((size_t)n * 4);
    int*    counts  = (int*)   alloc((size_t)flat * 4);
    int*    offsets = (int*)   alloc((size_t)flat * 4);
    int*    bsum    = (int*)   alloc((size_t)nb_scan * 4 + 256);
    int2*   binned  = (int2*)  alloc((size_t)E * 8);
    int*    col     = (int*)   alloc((size_t)E * 4);
    half_t* W1T     = (half_t*)alloc((size_t)256 * HID * 2);
    half_t* WcatT   = (half_t*)alloc((size_t)HID * HID * 2);
    half_t* hs      = (half_t*)alloc((size_t)n * HID * 2);  // gemm1 out, chunk-major [8][n][16]
    half_t* h1s     = (half_t*)alloc((size_t)n * HID * 2);  // relu out, chunk-major
    half_t* agg2    = hs;                                   // alias: hs dead after agg1

    float* out_mu  = (float*)d_out;
    float* out_sig = (float*)d_out + (size_t)n * DOUT;

    // CSR build
    bincount_kernel<<<nblocks, 256, 0, stream>>>(dst, counts, E, nblocks, NB);
    scan1_kernel<<<nb_scan, 256, 0, stream>>>(counts, offsets, bsum, flat);
    scan2_kernel<<<1, 1024, 0, stream>>>(bsum, nb_scan);
    scan3_kernel<<<(flat + 255) / 256, 256, 0, stream>>>(offsets, bsum, flat);
    binscatter_kernel<<<nblocks, 1024, 0, stream>>>(src, dst, offsets, binned, E, nblocks, NB);
    csrbuild_kernel<<<NB, 256, 0, stream>>>(binned, offsets, rowptr, col, dis, E, nblocks, NB, n);

    // weights
    w1t_kernel<<<(256 * HID) / 256, 256, 0, stream>>>(W1, W1T);
    wcatt_kernel<<<(HID * HID) / 256, 256, 0, stream>>>(Wmu, Wvar, WcatT);

    // dense + sparse pipeline
    const int aggGrid = ((n + 63) / 64) * 8;   // node-blocks (64 nodes) x 8 chunks
    gemm1_mfma<<<(n + 63) / 64, 256, 0, stream>>>(x, W1T, dis, hs, n);
    agg_kernel<true><<<aggGrid, 256, 0, stream>>>(rowptr, col, dis, hs, h1s, b1, n);
    agg_kernel<false><<<aggGrid, 256, 0, stream>>>(rowptr, col, dis, h1s, agg2, nullptr, n);
    gemm2_mfma<<<(n + 63) / 64, 256, 0, stream>>>(agg2, WcatT, bmu, bvar, out_mu, out_sig, n);
}

// Round 6
// 193.243 us; speedup vs baseline: 1.2738x; 1.2738x over previous
//
#include <hip/hip_runtime.h>

// VGAE GCN encoder: radix-binned CSR build (staged, coalesced) + 2-way
// XCD-group-pinned feature-chunked CSR gather aggregation + fp16 MFMA GEMMs.
// n=100000, f=256, hid=128, dout=64, E=1.6M (read from in_sizes).
//
// Algebra (norm-folded): hs = (X@W1)*dis (fp16);
//   agg1: acc_i = hs_i + sum_{s in N(i)} hs_s ; h1s_i = relu(dis_i*acc_i + b1)*dis_i
//   agg2: agg2_i = dis_i*(h1s_i + sum h1s_s)  ; out = agg2 @ [Wmu|Wvar] + bias
//
// Established by r1-r5 (measured):
//   - agg payload/segment size is the lever: 256B/no-chunk=60us,
//     128B/2-way=~52us (r4, best), 32B/8-way=81us (r5: transaction-bound,
//     FETCH 52MB @ 0.64 TB/s, VALU 43% -> neither BW nor VALU wall).
//   - NT col loads are poison (r2/r3): 12.8M uncached 4B fabric round-trips;
//     plain cached col gets ~17 reads/line via L1/L2.
//   - 2-way chunk [2][n][64], chunk=(bid>>2)&1 -> XCD groups {0-3}/{4-7},
//     12.8MB working set per XCD halves L2 misses vs unchunked.
//   - register accumulation per node; NO cross-lane reduce (r2 regression),
//     NO LDS atomics (r6-prev 20x regression).
// Round-12: r4 + (a) 8 lanes x f16x8 per node (same 128B/edge segment, 2x
// edges per wave-gather instruction -> half the gather-issue cost), (b) fold
// scan3 into binscatter/csrbuild offset reads, (c) merge weight-prep kernels.

#define HID 128
#define DOUT 64
#define NB_SHIFT 8          // 256 nodes per bucket
#define CHUNK 8192          // edges per binning block
#define MAXNB 400           // max buckets (n <= 102400)

typedef _Float16 half_t;
typedef half_t f16x4 __attribute__((ext_vector_type(4)));
typedef half_t f16x8 __attribute__((ext_vector_type(8)));
typedef float  f32x4 __attribute__((ext_vector_type(4)));

// ==================== CSR build ====================

__global__ __launch_bounds__(256) void bincount_kernel(const int* __restrict__ dst,
                                                       int* __restrict__ counts,
                                                       int E, int nblocks, int NB) {
    __shared__ int hist[MAXNB];
    const int b = blockIdx.x;
    for (int t = threadIdx.x; t < NB; t += 256) hist[t] = 0;
    __syncthreads();
    const int beg = b * CHUNK;
    const int end = min(E, beg + CHUNK);
    for (int e = beg + threadIdx.x; e < end; e += 256)
        atomicAdd(&hist[dst[e] >> NB_SHIFT], 1);
    __syncthreads();
    for (int t = threadIdx.x; t < NB; t += 256)
        counts[t * nblocks + b] = hist[t];
}

__global__ __launch_bounds__(256) void scan1_kernel(const int* __restrict__ in,
                                                    int* __restrict__ out,
                                                    int* __restrict__ bsum, int n) {
    __shared__ int s[256];
    int b = blockIdx.x, t = threadIdx.x;
    int base = b * 1024 + t * 4;
    int v0 = 0, v1 = 0, v2 = 0, v3 = 0;
    if (base + 0 < n) v0 = in[base + 0];
    if (base + 1 < n) v1 = in[base + 1];
    if (base + 2 < n) v2 = in[base + 2];
    if (base + 3 < n) v3 = in[base + 3];
    int tsum = v0 + v1 + v2 + v3;
    s[t] = tsum;
    __syncthreads();
    for (int off = 1; off < 256; off <<= 1) {
        int x = (t >= off) ? s[t - off] : 0;
        __syncthreads();
        s[t] += x;
        __syncthreads();
    }
    int excl = s[t] - tsum;
    if (base + 0 < n) out[base + 0] = excl;
    if (base + 1 < n) out[base + 1] = excl + v0;
    if (base + 2 < n) out[base + 2] = excl + v0 + v1;
    if (base + 3 < n) out[base + 3] = excl + v0 + v1 + v2;
    if (t == 255) bsum[b] = s[255];
}

// parallel single-block scan of block sums (nb <= 1024)
__global__ __launch_bounds__(1024) void scan2_kernel(int* __restrict__ bsum, int nb) {
    __shared__ int s[1024];
    int t = threadIdx.x;
    int v = (t < nb) ? bsum[t] : 0;
    s[t] = v;
    __syncthreads();
    for (int off = 1; off < 1024; off <<= 1) {
        int x = (t >= off) ? s[t - off] : 0;
        __syncthreads();
        s[t] += x;
        __syncthreads();
    }
    if (t < nb) bsum[t] = s[t] - v;   // exclusive
}

// LDS-staged binscatter: counting-sort the 8192-edge chunk in LDS, then write
// each (bucket,chunk) segment contiguously -> write amplification ~1.
// offsets are per-1024-chunk partial scans; bsum[idx>>10] completes them here
// (scan3 folded in).
__global__ __launch_bounds__(1024) void binscatter_kernel(const int* __restrict__ src,
                                                          const int* __restrict__ dst,
                                                          const int* __restrict__ offsets,
                                                          const int* __restrict__ bsum,
                                                          int2* __restrict__ binned,
                                                          int E, int nblocks, int NB) {
    __shared__ int  lhist[1024];
    __shared__ int  lbase[1024];
    __shared__ int  cur[1024];
    __shared__ int  goff[MAXNB];
    __shared__ int2 staged[CHUNK];
    const int b = blockIdx.x, t = threadIdx.x;
    const int beg = b * CHUNK;
    const int end = min(E, beg + CHUNK);
    const int ne  = end - beg;

    lhist[t] = 0;
    for (int k = t; k < NB; k += 1024) {
        int idx = k * nblocks + b;
        goff[k] = offsets[idx] + bsum[idx >> 10];
    }
    __syncthreads();

    // pass 1: histogram (edges kept in registers)
    int2 regs[8];
    #pragma unroll
    for (int j = 0; j < 8; j++) {
        int e = beg + t + j * 1024;
        if (e < end) {
            regs[j] = make_int2(src[e], dst[e]);
            atomicAdd(&lhist[regs[j].y >> NB_SHIFT], 1);
        }
    }
    __syncthreads();

    // inclusive scan of lhist -> exclusive bases
    int hv = lhist[t];
    for (int off = 1; off < 1024; off <<= 1) {
        int x = (t >= off) ? lhist[t - off] : 0;
        __syncthreads();
        lhist[t] += x;
        __syncthreads();
    }
    lbase[t] = lhist[t] - hv;
    cur[t]   = lhist[t] - hv;
    __syncthreads();

    // pass 2: place into LDS staging at local rank
    #pragma unroll
    for (int j = 0; j < 8; j++) {
        int e = beg + t + j * 1024;
        if (e < end) {
            int pos = atomicAdd(&cur[regs[j].y >> NB_SHIFT], 1);
            staged[pos] = regs[j];
        }
    }
    __syncthreads();

    // pass 3: linear write-out; consecutive t -> consecutive global addrs per segment
    #pragma unroll
    for (int j = 0; j < 8; j++) {
        int tt = t + j * 1024;
        if (tt < ne) {
            int2 sd = staged[tt];
            int bkt = sd.y >> NB_SHIFT;
            binned[goff[bkt] + (tt - lbase[bkt])] = sd;
        }
    }
}

// one WG per 256-node bucket: local degree hist -> local scan -> dis/rowptr_end
// (coalesced) -> place col within the bucket's 16KB window.
__global__ __launch_bounds__(256) void csrbuild_kernel(const int2* __restrict__ binned,
                                                       const int* __restrict__ offsets,
                                                       const int* __restrict__ bsum,
                                                       int* __restrict__ rowptr_end,
                                                       int* __restrict__ colA,
                                                       float* __restrict__ dis,
                                                       int E, int nblocks, int NB, int n) {
    __shared__ int deg[256];
    __shared__ int sc[256];
    __shared__ int cur[256];
    const int b = blockIdx.x;
    const int t = threadIdx.x;
    const int i0 = b * nblocks;
    const int base = offsets[i0] + bsum[i0 >> 10];
    int bend;
    if (b + 1 < NB) { int i1 = (b + 1) * nblocks; bend = offsets[i1] + bsum[i1 >> 10]; }
    else            bend = E;

    deg[t] = 0;
    __syncthreads();
    for (int e = base + t; e < bend; e += 256)
        atomicAdd(&deg[binned[e].y & 255], 1);
    __syncthreads();

    int v = deg[t];
    sc[t] = v;
    __syncthreads();
    for (int off = 1; off < 256; off <<= 1) {
        int x = (t >= off) ? sc[t - off] : 0;
        __syncthreads();
        sc[t] += x;
        __syncthreads();
    }
    int incl = sc[t];
    int node = (b << NB_SHIFT) + t;
    if (node < n) {
        rowptr_end[node] = base + incl;
        dis[node] = rsqrtf((float)v + 1.0f);
    }
    cur[t] = base + incl - v;
    __syncthreads();

    for (int e = base + t; e < bend; e += 256) {
        int2 sd = binned[e];
        int pos = atomicAdd(&cur[sd.y & 255], 1);
        colA[pos] = sd.x;
    }
}

// ==================== weight prep (merged) ====================
__global__ void wprep_kernel(const float* __restrict__ W1,
                             const float* __restrict__ Wmu,
                             const float* __restrict__ Wvar,
                             half_t* __restrict__ W1T,
                             half_t* __restrict__ WcatT) {
    int i = blockIdx.x * blockDim.x + threadIdx.x;
    if (i < 256 * HID) {                     // W1 [256,128] -> W1T [128,256]
        int k = i >> 7, nn = i & 127;
        W1T[nn * 256 + k] = (half_t)W1[i];
    } else {                                 // [Wmu|Wvar] [128,128] -> WcatT
        int j = i - 256 * HID;
        int k = j >> 7, nn = j & 127;
        float v = (nn < DOUT) ? Wmu[k * DOUT + nn] : Wvar[k * DOUT + (nn - DOUT)];
        WcatT[nn * 128 + k] = (half_t)v;
    }
}

// ==================== MFMA GEMM1 (register-prefetch pipelined) ====================
// hs[half][M][64](fp16) = (A[M,256](fp32) @ W1T^T) * dis[row], half-chunk-major.
__global__ __launch_bounds__(256) void gemm1_mfma(const float* __restrict__ A,
                                                  const half_t* __restrict__ BT,
                                                  const float* __restrict__ dis,
                                                  half_t* __restrict__ C, int M) {
    __shared__ half_t As[64][72];
    __shared__ half_t Bs[128][72];
    const int tid = threadIdx.x;
    const int block_row = blockIdx.x * 64;
    const int wave = tid >> 6, lane = tid & 63;
    const int wm = (wave & 1) * 32, wn = (wave >> 1) * 64;
    const int l16 = lane & 15, quad = lane >> 4;

    f32x4 acc[2][4] = {};
    float4 pa[4];
    f16x8  pb[4];

    #pragma unroll
    for (int i = 0; i < 4; i++) {
        int idx = tid + i * 256;
        int r = idx >> 4, c = idx & 15;
        int row = block_row + r; row = row < M ? row : M - 1;
        pa[i] = ((const float4*)(A + (size_t)row * 256))[c];
    }
    #pragma unroll
    for (int i = 0; i < 4; i++) {
        int idx = tid + i * 256;
        int nr = idx >> 3, kc = idx & 7;
        pb[i] = *(const f16x8*)(BT + (size_t)nr * 256 + kc * 8);
    }

    for (int k0 = 0; k0 < 256; k0 += 64) {
        #pragma unroll
        for (int i = 0; i < 4; i++) {
            int idx = tid + i * 256;
            int r = idx >> 4, c = idx & 15;
            f16x4 hv = { (half_t)pa[i].x, (half_t)pa[i].y, (half_t)pa[i].z, (half_t)pa[i].w };
            *(f16x4*)(&As[r][c * 4]) = hv;
        }
        #pragma unroll
        for (int i = 0; i < 4; i++) {
            int idx = tid + i * 256;
            int nr = idx >> 3, kc = idx & 7;
            *(f16x8*)(&Bs[nr][kc * 8]) = pb[i];
        }
        __syncthreads();

        if (k0 < 192) {
            #pragma unroll
            for (int i = 0; i < 4; i++) {
                int idx = tid + i * 256;
                int r = idx >> 4, c = idx & 15;
                int row = block_row + r; row = row < M ? row : M - 1;
                pa[i] = ((const float4*)(A + (size_t)row * 256 + k0 + 64))[c];
            }
            #pragma unroll
            for (int i = 0; i < 4; i++) {
                int idx = tid + i * 256;
                int nr = idx >> 3, kc = idx & 7;
                pb[i] = *(const f16x8*)(BT + (size_t)nr * 256 + k0 + 64 + kc * 8);
            }
        }

        #pragma unroll
        for (int ks = 0; ks < 2; ks++) {
            f16x8 af[2], bf[4];
            #pragma unroll
            for (int mt = 0; mt < 2; mt++)
                af[mt] = *(const f16x8*)(&As[wm + mt * 16 + l16][ks * 32 + quad * 8]);
            #pragma unroll
            for (int nt = 0; nt < 4; nt++)
                bf[nt] = *(const f16x8*)(&Bs[wn + nt * 16 + l16][ks * 32 + quad * 8]);
            #pragma unroll
            for (int mt = 0; mt < 2; mt++)
                #pragma unroll
                for (int nt = 0; nt < 4; nt++)
                    acc[mt][nt] = __builtin_amdgcn_mfma_f32_16x16x32_f16(af[mt], bf[nt], acc[mt][nt], 0, 0, 0);
        }
        __syncthreads();
    }

    #pragma unroll
    for (int mt = 0; mt < 2; mt++) {
        #pragma unroll
        for (int r = 0; r < 4; r++) {
            int row = block_row + wm + mt * 16 + quad * 4 + r;
            if (row < M) {
                float d = dis[row];
                #pragma unroll
                for (int nt = 0; nt < 4; nt++) {
                    int col = wn + nt * 16 + l16;
                    C[((size_t)(col >> 6) * M + row) * 64 + (col & 63)] = (half_t)(acc[mt][nt][r] * d);
                }
            }
        }
    }
}

// ==================== MFMA GEMM2 (pipelined; half-chunk-major A) ====================
__global__ __launch_bounds__(256) void gemm2_mfma(const half_t* __restrict__ A,
                                                  const half_t* __restrict__ BT,
                                                  const float* __restrict__ bmu,
                                                  const float* __restrict__ bvar,
                                                  float* __restrict__ out_mu,
                                                  float* __restrict__ out_sig, int M) {
    __shared__ half_t As[64][72];
    __shared__ half_t Bs[128][72];
    const int tid = threadIdx.x;
    const int block_row = blockIdx.x * 64;
    const int wave = tid >> 6, lane = tid & 63;
    const int wm = (wave & 1) * 32, wn = (wave >> 1) * 64;
    const int l16 = lane & 15, quad = lane >> 4;

    f32x4 acc[2][4] = {};
    f16x8 pa[2], pb[4];

    // A[half][M][64]: k0=0 tile reads half 0, k0=64 tile reads half 1.
    #pragma unroll
    for (int i = 0; i < 2; i++) {
        int idx = tid + i * 256;
        int r = idx >> 3, kc = idx & 7;
        int row = block_row + r; row = row < M ? row : M - 1;
        pa[i] = *(const f16x8*)(A + (size_t)row * 64 + kc * 8);
    }
    #pragma unroll
    for (int i = 0; i < 4; i++) {
        int idx = tid + i * 256;
        int nr = idx >> 3, kc = idx & 7;
        pb[i] = *(const f16x8*)(BT + (size_t)nr * 128 + kc * 8);
    }

    for (int k0 = 0; k0 < 128; k0 += 64) {
        #pragma unroll
        for (int i = 0; i < 2; i++) {
            int idx = tid + i * 256;
            int r = idx >> 3, kc = idx & 7;
            *(f16x8*)(&As[r][kc * 8]) = pa[i];
        }
        #pragma unroll
        for (int i = 0; i < 4; i++) {
            int idx = tid + i * 256;
            int nr = idx >> 3, kc = idx & 7;
            *(f16x8*)(&Bs[nr][kc * 8]) = pb[i];
        }
        __syncthreads();

        if (k0 < 64) {
            #pragma unroll
            for (int i = 0; i < 2; i++) {
                int idx = tid + i * 256;
                int r = idx >> 3, kc = idx & 7;
                int row = block_row + r; row = row < M ? row : M - 1;
                pa[i] = *(const f16x8*)(A + ((size_t)M + row) * 64 + kc * 8);
            }
            #pragma unroll
            for (int i = 0; i < 4; i++) {
                int idx = tid + i * 256;
                int nr = idx >> 3, kc = idx & 7;
                pb[i] = *(const f16x8*)(BT + (size_t)nr * 128 + 64 + kc * 8);
            }
        }

        #pragma unroll
        for (int ks = 0; ks < 2; ks++) {
            f16x8 af[2], bf[4];
            #pragma unroll
            for (int mt = 0; mt < 2; mt++)
                af[mt] = *(const f16x8*)(&As[wm + mt * 16 + l16][ks * 32 + quad * 8]);
            #pragma unroll
            for (int nt = 0; nt < 4; nt++)
                bf[nt] = *(const f16x8*)(&Bs[wn + nt * 16 + l16][ks * 32 + quad * 8]);
            #pragma unroll
            for (int mt = 0; mt < 2; mt++)
                #pragma unroll
                for (int nt = 0; nt < 4; nt++)
                    acc[mt][nt] = __builtin_amdgcn_mfma_f32_16x16x32_f16(af[mt], bf[nt], acc[mt][nt], 0, 0, 0);
        }
        __syncthreads();
    }

    float bias[4];
    int cols[4];
    #pragma unroll
    for (int nt = 0; nt < 4; nt++) {
        int col = wn + nt * 16 + l16;
        cols[nt] = col;
        bias[nt] = (col < DOUT) ? bmu[col] : bvar[col - DOUT];
    }

    #pragma unroll
    for (int mt = 0; mt < 2; mt++) {
        #pragma unroll
        for (int r = 0; r < 4; r++) {
            int row = block_row + wm + mt * 16 + quad * 4 + r;
            if (row < M) {
                #pragma unroll
                for (int nt = 0; nt < 4; nt++) {
                    int col = cols[nt];
                    float v = acc[mt][nt][r] + bias[nt];
                    if (col < DOUT) out_mu[(size_t)row * DOUT + col] = v;
                    else            out_sig[(size_t)row * DOUT + (col - DOUT)] = v;
                }
            }
        }
    }
}

// ==================== aggregation (2-way XCD-group chunks, wide lanes) ====================
// hin/hout half-chunk-major [2][n][64] fp16.  chunk = (bid>>2)&1: XCD group
// {0..3} owns half 0, {4..7} half 1 (12.8MB working set per XCD vs 25.6).
// 8 lanes own one node's 64-feat half via f16x8 (16B/lane; 128B contiguous
// per edge — same segment size as r4, 2x edges per wave-gather instruction).
// Engine: 8-deep clamped col batch (PLAIN cached) + 8-deep gather batch,
// register accumulation.  v_fma_mix_f32 accumulate; flag doubles as tail mask.
__device__ __forceinline__ void acc_mix8(float* a, f16x8 v, float fl) {
    union { f16x8 h; int i[4]; } u; u.h = v;
    #pragma unroll
    for (int k = 0; k < 4; k++) {
        asm("v_fma_mix_f32 %0, %1, %2, %0 op_sel_hi:[1,0,0]"
            : "+v"(a[2 * k]) : "v"(u.i[k]), "v"(fl));
        asm("v_fma_mix_f32 %0, %1, %2, %0 op_sel:[1,0,0] op_sel_hi:[1,0,0]"
            : "+v"(a[2 * k + 1]) : "v"(u.i[k]), "v"(fl));
    }
}

template <bool LAYER1>
__global__ __launch_bounds__(256) void agg_kernel(const int* __restrict__ rowptr_end,
                                                  const int* __restrict__ col,
                                                  const float* __restrict__ dis,
                                                  const half_t* __restrict__ hin,
                                                  half_t* __restrict__ hout,
                                                  const float* __restrict__ bias, int n) {
    const int bid   = blockIdx.x;
    const int chunk = (bid >> 2) & 1;                 // XCD group {0-3}->0, {4-7}->1
    const int nb    = (bid >> 3) * 4 + (bid & 3);     // node-block within chunk
    const int node  = nb * 32 + (threadIdx.x >> 3);   // 32 nodes per block
    if (node >= n) return;
    const int lane8 = threadIdx.x & 7;                // f16x8 (16B) within 64-feat half

    const f16x8* hc = (const f16x8*)(hin + (size_t)chunk * n * 64);

    int beg = (node == 0) ? 0 : rowptr_end[node - 1];
    int end = rowptr_end[node];

    float one = 1.0f;
    float a[8] = {};
    acc_mix8(a, hc[(size_t)node * 8 + lane8], one);   // self term

    int deg = end - beg;
    if (deg > 0) {
        const int last = end - 1;
        int c[8];
        #pragma unroll
        for (int j = 0; j < 8; j++) c[j] = col[min(beg + j, last)];

        int ng = (deg + 7) >> 3;
        int e = beg;
        for (int g = 0; g < ng; g++) {
            // issue the 8 long-latency gathers first (128B contiguous each)
            f16x8 v[8];
            #pragma unroll
            for (int j = 0; j < 8; j++) v[j] = hc[(size_t)c[j] * 8 + lane8];

            int enext = e + 8;
            if (g + 1 < ng) {
                // prefetch next col batch while gathers are in flight
                #pragma unroll
                for (int j = 0; j < 8; j++) c[j] = col[min(enext + j, last)];
                #pragma unroll
                for (int j = 0; j < 8; j++) acc_mix8(a, v[j], one);
            } else {
                int rem = end - e;   // 1..8 valid edges in the final group
                #pragma unroll
                for (int j = 0; j < 8; j++) {
                    float fl = (j < rem) ? 1.0f : 0.0f;
                    acc_mix8(a, v[j], fl);
                }
            }
            e = enext;
        }
    }

    float di = dis[node];
    if (LAYER1) {
        const float4 b0 = ((const float4*)bias)[chunk * 16 + lane8 * 2];
        const float4 b1 = ((const float4*)bias)[chunk * 16 + lane8 * 2 + 1];
        float bb[8] = { b0.x, b0.y, b0.z, b0.w, b1.x, b1.y, b1.z, b1.w };
        #pragma unroll
        for (int k = 0; k < 8; k++) {
            float t = a[k] * di + bb[k];
            a[k] = (t > 0.f ? t : 0.f) * di;
        }
    } else {
        #pragma unroll
        for (int k = 0; k < 8; k++) a[k] *= di;
    }
    f16x8 o = { (half_t)a[0], (half_t)a[1], (half_t)a[2], (half_t)a[3],
                (half_t)a[4], (half_t)a[5], (half_t)a[6], (half_t)a[7] };
    ((f16x8*)(hout + (size_t)chunk * n * 64))[(size_t)node * 8 + lane8] = o;
}

extern "C" void kernel_launch(void* const* d_in, const int* in_sizes, int n_in,
                              void* d_out, int out_size, void* d_ws, size_t ws_size,
                              hipStream_t stream) {
    const float* x    = (const float*)d_in[0];
    const int*   ei   = (const int*)d_in[1];
    const float* W1   = (const float*)d_in[2];
    const float* b1   = (const float*)d_in[3];
    const float* Wmu  = (const float*)d_in[4];
    const float* bmu  = (const float*)d_in[5];
    const float* Wvar = (const float*)d_in[6];
    const float* bvar = (const float*)d_in[7];

    const int n = in_sizes[0] / 256;     // 100000
    const int E = in_sizes[1] / 2;       // 1600000
    const int* src = ei;
    const int* dst = ei + E;

    const int NB      = (n + 255) >> NB_SHIFT;       // 391
    const int nblocks = (E + CHUNK - 1) / CHUNK;     // 196
    const int flat    = NB * nblocks;
    const int nb_scan = (flat + 1023) / 1024;        // 75 (<= 1024)

    char* ws = (char*)d_ws;
    size_t off = 0;
    auto alloc = [&](size_t bytes) { void* p = ws + off; off = (off + bytes + 255) & ~(size_t)255; return p; };
    float*  dis     = (float*) alloc((size_t)n * 4);
    int*    rowptr  = (int*)   alloc((size_t)n * 4);
    int*    counts  = (int*)   alloc((size_t)flat * 4);
    int*    offsets = (int*)   alloc((size_t)flat * 4);
    int*    bsum    = (int*)   alloc((size_t)nb_scan * 4 + 256);
    int2*   binned  = (int2*)  alloc((size_t)E * 8);
    int*    col     = (int*)   alloc((size_t)E * 4);
    half_t* W1T     = (half_t*)alloc((size_t)256 * HID * 2);
    half_t* WcatT   = (half_t*)alloc((size_t)HID * HID * 2);
    half_t* hs      = (half_t*)alloc((size_t)n * HID * 2);  // gemm1 out, [2][n][64]
    half_t* h1s     = (half_t*)alloc((size_t)n * HID * 2);  // relu out, [2][n][64]
    half_t* agg2    = hs;                                   // alias: hs dead after agg1

    float* out_mu  = (float*)d_out;
    float* out_sig = (float*)d_out + (size_t)n * DOUT;

    // CSR build (scan3 folded into binscatter/csrbuild via bsum)
    bincount_kernel<<<nblocks, 256, 0, stream>>>(dst, counts, E, nblocks, NB);
    scan1_kernel<<<nb_scan, 256, 0, stream>>>(counts, offsets, bsum, flat);
    scan2_kernel<<<1, 1024, 0, stream>>>(bsum, nb_scan);
    binscatter_kernel<<<nblocks, 1024, 0, stream>>>(src, dst, offsets, bsum, binned, E, nblocks, NB);
    csrbuild_kernel<<<NB, 256, 0, stream>>>(binned, offsets, bsum, rowptr, col, dis, E, nblocks, NB, n);

    // weights (merged)
    wprep_kernel<<<(256 * HID + HID * HID) / 256, 256, 0, stream>>>(W1, Wmu, Wvar, W1T, WcatT);

    // dense + sparse pipeline
    // agg grid: groups of 8 blocks = {4 node-blocks x chunk0, 4 x chunk1},
    // 32 nodes per block -> each group covers 128 nodes per chunk.
    const int aggGrid = ((n + 127) / 128) * 8;
    gemm1_mfma<<<(n + 63) / 64, 256, 0, stream>>>(x, W1T, dis, hs, n);
    agg_kernel<true><<<aggGrid, 256, 0, stream>>>(rowptr, col, dis, hs, h1s, b1, n);
    agg_kernel<false><<<aggGrid, 256, 0, stream>>>(rowptr, col, dis, h1s, agg2, nullptr, n);
    gemm2_mfma<<<(n + 63) / 64, 256, 0, stream>>>(agg2, WcatT, bmu, bvar, out_mu, out_sig, n);
}

// Round 7
// 192.749 us; speedup vs baseline: 1.2770x; 1.0026x over previous
//
#include <hip/hip_runtime.h>

// VGAE GCN encoder: radix-binned CSR build (staged, coalesced, shfl-scanned) +
// 2-way XCD-group-pinned feature-chunked CSR gather aggregation + fp16 MFMA
// GEMMs.  n=100000, f=256, hid=128, dout=64, E=1.6M (read from in_sizes).
//
// Algebra (norm-folded): hs = (X@W1)*dis (fp16);
//   agg1: acc_i = hs_i + sum_{s in N(i)} hs_s ; h1s_i = relu(dis_i*acc_i + b1)*dis_i
//   agg2: agg2_i = dis_i*(h1s_i + sum h1s_s)  ; out = agg2 @ [Wmu|Wvar] + bias
//
// Established by r1-r6 (measured):
//   - agg payload/segment size is the lever: 256B/no-chunk=60us,
//     128B/2-way=~48-52us (r4/r6, best), 32B/8-way=81us (transaction-bound).
//   - NT *loads* for col are poison (r2/r3): uncached 4B fabric round-trips.
//   - 2-way chunk [2][n][64], chunk=(bid>>2)&1 -> XCD groups {0-3}/{4-7}.
//   - register accumulation; NO cross-lane reduce; NO LDS-atomic aggregation.
//   - aggs sit near the L3 random-service floor (r6: only +5us from 2x fewer
//     gather instructions) -> remaining levers are residency, not scheduling.
// Round-13 (this file): CSR chain was scan/atomic-bound (51MB of traffic but
// ~45us): (a) binscatter pass-1 histogram == counts[] already computed by
// bincount -> load it, drop 8192 LDS atomics; (b) 1024/256-wide ladder scans
// (20/16 barriers) -> 2-level shfl wave scans (3 barriers); (c) agg2 output
// via nontemporal STORE (consumed sequentially by gemm2; stops write
// allocations evicting the gather working set).  NT stores != NT loads.

#define HID 128
#define DOUT 64
#define NB_SHIFT 8          // 256 nodes per bucket
#define CHUNK 8192          // edges per binning block
#define MAXNB 400           // max buckets (n <= 102400)

typedef _Float16 half_t;
typedef half_t f16x4 __attribute__((ext_vector_type(4)));
typedef half_t f16x8 __attribute__((ext_vector_type(8)));
typedef float  f32x4 __attribute__((ext_vector_type(4)));

// inclusive scan of v across the 64-lane wave
__device__ __forceinline__ int wave_incl_scan(int v, int lane) {
    #pragma unroll
    for (int off = 1; off < 64; off <<= 1) {
        int x = __shfl_up(v, off);
        if (lane >= off) v += x;
    }
    return v;
}

// ==================== CSR build ====================

__global__ __launch_bounds__(256) void bincount_kernel(const int* __restrict__ dst,
                                                       int* __restrict__ counts,
                                                       int E, int nblocks, int NB) {
    __shared__ int hist[MAXNB];
    const int b = blockIdx.x;
    for (int t = threadIdx.x; t < NB; t += 256) hist[t] = 0;
    __syncthreads();
    const int beg = b * CHUNK;
    const int end = min(E, beg + CHUNK);
    for (int e = beg + threadIdx.x; e < end; e += 256)
        atomicAdd(&hist[dst[e] >> NB_SHIFT], 1);
    __syncthreads();
    for (int t = threadIdx.x; t < NB; t += 256)
        counts[t * nblocks + b] = hist[t];
}

__global__ __launch_bounds__(256) void scan1_kernel(const int* __restrict__ in,
                                                    int* __restrict__ out,
                                                    int* __restrict__ bsum, int n) {
    __shared__ int wsum[4];
    int b = blockIdx.x, t = threadIdx.x;
    int lane = t & 63, wid = t >> 6;
    int base = b * 1024 + t * 4;
    int v0 = 0, v1 = 0, v2 = 0, v3 = 0;
    if (base + 0 < n) v0 = in[base + 0];
    if (base + 1 < n) v1 = in[base + 1];
    if (base + 2 < n) v2 = in[base + 2];
    if (base + 3 < n) v3 = in[base + 3];
    int tsum = v0 + v1 + v2 + v3;
    int incl = wave_incl_scan(tsum, lane);
    if (lane == 63) wsum[wid] = incl;
    __syncthreads();
    if (t < 4) {
        int v = wsum[t], s = v;
        #pragma unroll
        for (int off = 1; off < 4; off <<= 1) {
            int x = __shfl_up(s, off);
            if (t >= off) s += x;
        }
        wsum[t] = s - v;   // exclusive wave offset
    }
    __syncthreads();
    incl += wsum[wid];
    int excl = incl - tsum;
    if (base + 0 < n) out[base + 0] = excl;
    if (base + 1 < n) out[base + 1] = excl + v0;
    if (base + 2 < n) out[base + 2] = excl + v0 + v1;
    if (base + 3 < n) out[base + 3] = excl + v0 + v1 + v2;
    if (t == 255) bsum[b] = incl;
}

// parallel single-block scan of block sums (nb <= 1024)
__global__ __launch_bounds__(1024) void scan2_kernel(int* __restrict__ bsum, int nb) {
    __shared__ int s[1024];
    int t = threadIdx.x;
    int v = (t < nb) ? bsum[t] : 0;
    s[t] = v;
    __syncthreads();
    for (int off = 1; off < 1024; off <<= 1) {
        int x = (t >= off) ? s[t - off] : 0;
        __syncthreads();
        s[t] += x;
        __syncthreads();
    }
    if (t < nb) bsum[t] = s[t] - v;   // exclusive
}

// LDS-staged binscatter: counting-sort the 8192-edge chunk in LDS, then write
// each (bucket,chunk) segment contiguously -> write amplification ~1.
// Per-chunk bucket histogram == counts[] from bincount (loaded, not recomputed).
// offsets are per-1024-chunk partial scans; bsum[idx>>10] completes them.
__global__ __launch_bounds__(1024) void binscatter_kernel(const int* __restrict__ src,
                                                          const int* __restrict__ dst,
                                                          const int* __restrict__ counts,
                                                          const int* __restrict__ offsets,
                                                          const int* __restrict__ bsum,
                                                          int2* __restrict__ binned,
                                                          int E, int nblocks, int NB) {
    __shared__ int  lbase[1024];
    __shared__ int  cur[1024];
    __shared__ int  goff[MAXNB];
    __shared__ int  wsum[16];
    __shared__ int2 staged[CHUNK];
    const int b = blockIdx.x, t = threadIdx.x;
    const int lane = t & 63, wid = t >> 6;
    const int beg = b * CHUNK;
    const int end = min(E, beg + CHUNK);
    const int ne  = end - beg;

    for (int k = t; k < NB; k += 1024) {
        int idx = k * nblocks + b;
        goff[k] = offsets[idx] + bsum[idx >> 10];
    }

    // this chunk's bucket histogram, straight from bincount's output
    int cnt = (t < NB) ? counts[t * nblocks + b] : 0;
    int incl = wave_incl_scan(cnt, lane);
    if (lane == 63) wsum[wid] = incl;

    // load edges into registers while the scan settles
    int2 regs[8];
    #pragma unroll
    for (int j = 0; j < 8; j++) {
        int e = beg + t + j * 1024;
        if (e < end) regs[j] = make_int2(src[e], dst[e]);
    }
    __syncthreads();
    if (t < 16) {
        int v = wsum[t], s = v;
        #pragma unroll
        for (int off = 1; off < 16; off <<= 1) {
            int x = __shfl_up(s, off);
            if (t >= off) s += x;
        }
        wsum[t] = s - v;   // exclusive wave offset
    }
    __syncthreads();
    incl += wsum[wid];
    int myb = incl - cnt;
    lbase[t] = myb;
    cur[t]   = myb;
    __syncthreads();

    // pass 2: place into LDS staging at local rank
    #pragma unroll
    for (int j = 0; j < 8; j++) {
        int e = beg + t + j * 1024;
        if (e < end) {
            int pos = atomicAdd(&cur[regs[j].y >> NB_SHIFT], 1);
            staged[pos] = regs[j];
        }
    }
    __syncthreads();

    // pass 3: linear write-out; consecutive t -> consecutive global addrs per segment
    #pragma unroll
    for (int j = 0; j < 8; j++) {
        int tt = t + j * 1024;
        if (tt < ne) {
            int2 sd = staged[tt];
            int bkt = sd.y >> NB_SHIFT;
            binned[goff[bkt] + (tt - lbase[bkt])] = sd;
        }
    }
}

// one WG per 256-node bucket: local degree hist -> shfl scan -> dis/rowptr_end
// (coalesced) -> place col within the bucket's 16KB window.
__global__ __launch_bounds__(256) void csrbuild_kernel(const int2* __restrict__ binned,
                                                       const int* __restrict__ offsets,
                                                       const int* __restrict__ bsum,
                                                       int* __restrict__ rowptr_end,
                                                       int* __restrict__ colA,
                                                       float* __restrict__ dis,
                                                       int E, int nblocks, int NB, int n) {
    __shared__ int deg[256];
    __shared__ int cur[256];
    __shared__ int wsum[4];
    const int b = blockIdx.x;
    const int t = threadIdx.x;
    const int lane = t & 63, wid = t >> 6;
    const int i0 = b * nblocks;
    const int base = offsets[i0] + bsum[i0 >> 10];
    int bend;
    if (b + 1 < NB) { int i1 = (b + 1) * nblocks; bend = offsets[i1] + bsum[i1 >> 10]; }
    else            bend = E;

    deg[t] = 0;
    __syncthreads();
    for (int e = base + t; e < bend; e += 256)
        atomicAdd(&deg[binned[e].y & 255], 1);
    __syncthreads();

    int v = deg[t];
    int incl = wave_incl_scan(v, lane);
    if (lane == 63) wsum[wid] = incl;
    __syncthreads();
    if (t < 4) {
        int vv = wsum[t], s = vv;
        #pragma unroll
        for (int off = 1; off < 4; off <<= 1) {
            int x = __shfl_up(s, off);
            if (t >= off) s += x;
        }
        wsum[t] = s - vv;
    }
    __syncthreads();
    incl += wsum[wid];

    int node = (b << NB_SHIFT) + t;
    if (node < n) {
        rowptr_end[node] = base + incl;
        dis[node] = rsqrtf((float)v + 1.0f);
    }
    cur[t] = base + incl - v;
    __syncthreads();

    for (int e = base + t; e < bend; e += 256) {
        int2 sd = binned[e];
        int pos = atomicAdd(&cur[sd.y & 255], 1);
        colA[pos] = sd.x;
    }
}

// ==================== weight prep (merged) ====================
__global__ void wprep_kernel(const float* __restrict__ W1,
                             const float* __restrict__ Wmu,
                             const float* __restrict__ Wvar,
                             half_t* __restrict__ W1T,
                             half_t* __restrict__ WcatT) {
    int i = blockIdx.x * blockDim.x + threadIdx.x;
    if (i < 256 * HID) {                     // W1 [256,128] -> W1T [128,256]
        int k = i >> 7, nn = i & 127;
        W1T[nn * 256 + k] = (half_t)W1[i];
    } else {                                 // [Wmu|Wvar] [128,128] -> WcatT
        int j = i - 256 * HID;
        int k = j >> 7, nn = j & 127;
        float v = (nn < DOUT) ? Wmu[k * DOUT + nn] : Wvar[k * DOUT + (nn - DOUT)];
        WcatT[nn * 128 + k] = (half_t)v;
    }
}

// ==================== MFMA GEMM1 (register-prefetch pipelined) ====================
// hs[half][M][64](fp16) = (A[M,256](fp32) @ W1T^T) * dis[row], half-chunk-major.
__global__ __launch_bounds__(256) void gemm1_mfma(const float* __restrict__ A,
                                                  const half_t* __restrict__ BT,
                                                  const float* __restrict__ dis,
                                                  half_t* __restrict__ C, int M) {
    __shared__ half_t As[64][72];
    __shared__ half_t Bs[128][72];
    const int tid = threadIdx.x;
    const int block_row = blockIdx.x * 64;
    const int wave = tid >> 6, lane = tid & 63;
    const int wm = (wave & 1) * 32, wn = (wave >> 1) * 64;
    const int l16 = lane & 15, quad = lane >> 4;

    f32x4 acc[2][4] = {};
    float4 pa[4];
    f16x8  pb[4];

    #pragma unroll
    for (int i = 0; i < 4; i++) {
        int idx = tid + i * 256;
        int r = idx >> 4, c = idx & 15;
        int row = block_row + r; row = row < M ? row : M - 1;
        pa[i] = ((const float4*)(A + (size_t)row * 256))[c];
    }
    #pragma unroll
    for (int i = 0; i < 4; i++) {
        int idx = tid + i * 256;
        int nr = idx >> 3, kc = idx & 7;
        pb[i] = *(const f16x8*)(BT + (size_t)nr * 256 + kc * 8);
    }

    for (int k0 = 0; k0 < 256; k0 += 64) {
        #pragma unroll
        for (int i = 0; i < 4; i++) {
            int idx = tid + i * 256;
            int r = idx >> 4, c = idx & 15;
            f16x4 hv = { (half_t)pa[i].x, (half_t)pa[i].y, (half_t)pa[i].z, (half_t)pa[i].w };
            *(f16x4*)(&As[r][c * 4]) = hv;
        }
        #pragma unroll
        for (int i = 0; i < 4; i++) {
            int idx = tid + i * 256;
            int nr = idx >> 3, kc = idx & 7;
            *(f16x8*)(&Bs[nr][kc * 8]) = pb[i];
        }
        __syncthreads();

        if (k0 < 192) {
            #pragma unroll
            for (int i = 0; i < 4; i++) {
                int idx = tid + i * 256;
                int r = idx >> 4, c = idx & 15;
                int row = block_row + r; row = row < M ? row : M - 1;
                pa[i] = ((const float4*)(A + (size_t)row * 256 + k0 + 64))[c];
            }
            #pragma unroll
            for (int i = 0; i < 4; i++) {
                int idx = tid + i * 256;
                int nr = idx >> 3, kc = idx & 7;
                pb[i] = *(const f16x8*)(BT + (size_t)nr * 256 + k0 + 64 + kc * 8);
            }
        }

        #pragma unroll
        for (int ks = 0; ks < 2; ks++) {
            f16x8 af[2], bf[4];
            #pragma unroll
            for (int mt = 0; mt < 2; mt++)
                af[mt] = *(const f16x8*)(&As[wm + mt * 16 + l16][ks * 32 + quad * 8]);
            #pragma unroll
            for (int nt = 0; nt < 4; nt++)
                bf[nt] = *(const f16x8*)(&Bs[wn + nt * 16 + l16][ks * 32 + quad * 8]);
            #pragma unroll
            for (int mt = 0; mt < 2; mt++)
                #pragma unroll
                for (int nt = 0; nt < 4; nt++)
                    acc[mt][nt] = __builtin_amdgcn_mfma_f32_16x16x32_f16(af[mt], bf[nt], acc[mt][nt], 0, 0, 0);
        }
        __syncthreads();
    }

    #pragma unroll
    for (int mt = 0; mt < 2; mt++) {
        #pragma unroll
        for (int r = 0; r < 4; r++) {
            int row = block_row + wm + mt * 16 + quad * 4 + r;
            if (row < M) {
                float d = dis[row];
                #pragma unroll
                for (int nt = 0; nt < 4; nt++) {
                    int col = wn + nt * 16 + l16;
                    C[((size_t)(col >> 6) * M + row) * 64 + (col & 63)] = (half_t)(acc[mt][nt][r] * d);
                }
            }
        }
    }
}

// ==================== MFMA GEMM2 (pipelined; half-chunk-major A) ====================
__global__ __launch_bounds__(256) void gemm2_mfma(const half_t* __restrict__ A,
                                                  const half_t* __restrict__ BT,
                                                  const float* __restrict__ bmu,
                                                  const float* __restrict__ bvar,
                                                  float* __restrict__ out_mu,
                                                  float* __restrict__ out_sig, int M) {
    __shared__ half_t As[64][72];
    __shared__ half_t Bs[128][72];
    const int tid = threadIdx.x;
    const int block_row = blockIdx.x * 64;
    const int wave = tid >> 6, lane = tid & 63;
    const int wm = (wave & 1) * 32, wn = (wave >> 1) * 64;
    const int l16 = lane & 15, quad = lane >> 4;

    f32x4 acc[2][4] = {};
    f16x8 pa[2], pb[4];

    // A[half][M][64]: k0=0 tile reads half 0, k0=64 tile reads half 1.
    #pragma unroll
    for (int i = 0; i < 2; i++) {
        int idx = tid + i * 256;
        int r = idx >> 3, kc = idx & 7;
        int row = block_row + r; row = row < M ? row : M - 1;
        pa[i] = *(const f16x8*)(A + (size_t)row * 64 + kc * 8);
    }
    #pragma unroll
    for (int i = 0; i < 4; i++) {
        int idx = tid + i * 256;
        int nr = idx >> 3, kc = idx & 7;
        pb[i] = *(const f16x8*)(BT + (size_t)nr * 128 + kc * 8);
    }

    for (int k0 = 0; k0 < 128; k0 += 64) {
        #pragma unroll
        for (int i = 0; i < 2; i++) {
            int idx = tid + i * 256;
            int r = idx >> 3, kc = idx & 7;
            *(f16x8*)(&As[r][kc * 8]) = pa[i];
        }
        #pragma unroll
        for (int i = 0; i < 4; i++) {
            int idx = tid + i * 256;
            int nr = idx >> 3, kc = idx & 7;
            *(f16x8*)(&Bs[nr][kc * 8]) = pb[i];
        }
        __syncthreads();

        if (k0 < 64) {
            #pragma unroll
            for (int i = 0; i < 2; i++) {
                int idx = tid + i * 256;
                int r = idx >> 3, kc = idx & 7;
                int row = block_row + r; row = row < M ? row : M - 1;
                pa[i] = *(const f16x8*)(A + ((size_t)M + row) * 64 + kc * 8);
            }
            #pragma unroll
            for (int i = 0; i < 4; i++) {
                int idx = tid + i * 256;
                int nr = idx >> 3, kc = idx & 7;
                pb[i] = *(const f16x8*)(BT + (size_t)nr * 128 + 64 + kc * 8);
            }
        }

        #pragma unroll
        for (int ks = 0; ks < 2; ks++) {
            f16x8 af[2], bf[4];
            #pragma unroll
            for (int mt = 0; mt < 2; mt++)
                af[mt] = *(const f16x8*)(&As[wm + mt * 16 + l16][ks * 32 + quad * 8]);
            #pragma unroll
            for (int nt = 0; nt < 4; nt++)
                bf[nt] = *(const f16x8*)(&Bs[wn + nt * 16 + l16][ks * 32 + quad * 8]);
            #pragma unroll
            for (int mt = 0; mt < 2; mt++)
                #pragma unroll
                for (int nt = 0; nt < 4; nt++)
                    acc[mt][nt] = __builtin_amdgcn_mfma_f32_16x16x32_f16(af[mt], bf[nt], acc[mt][nt], 0, 0, 0);
        }
        __syncthreads();
    }

    float bias[4];
    int cols[4];
    #pragma unroll
    for (int nt = 0; nt < 4; nt++) {
        int col = wn + nt * 16 + l16;
        cols[nt] = col;
        bias[nt] = (col < DOUT) ? bmu[col] : bvar[col - DOUT];
    }

    #pragma unroll
    for (int mt = 0; mt < 2; mt++) {
        #pragma unroll
        for (int r = 0; r < 4; r++) {
            int row = block_row + wm + mt * 16 + quad * 4 + r;
            if (row < M) {
                #pragma unroll
                for (int nt = 0; nt < 4; nt++) {
                    int col = cols[nt];
                    float v = acc[mt][nt][r] + bias[nt];
                    if (col < DOUT) out_mu[(size_t)row * DOUT + col] = v;
                    else            out_sig[(size_t)row * DOUT + (col - DOUT)] = v;
                }
            }
        }
    }
}

// ==================== aggregation (2-way XCD-group chunks, wide lanes) ====================
// hin/hout half-chunk-major [2][n][64] fp16.  chunk = (bid>>2)&1: XCD group
// {0..3} owns half 0, {4..7} half 1 (12.8MB working set per XCD vs 25.6).
// 8 lanes own one node's 64-feat half via f16x8 (16B/lane; 128B contiguous
// per edge).  Engine: 8-deep clamped col batch (PLAIN cached) + 8-deep gather
// batch, register accumulation.  LAYER2 output is NT-stored (consumed
// sequentially by gemm2) to keep write allocations out of the gather L2 set.
__device__ __forceinline__ void acc_mix8(float* a, f16x8 v, float fl) {
    union { f16x8 h; int i[4]; } u; u.h = v;
    #pragma unroll
    for (int k = 0; k < 4; k++) {
        asm("v_fma_mix_f32 %0, %1, %2, %0 op_sel_hi:[1,0,0]"
            : "+v"(a[2 * k]) : "v"(u.i[k]), "v"(fl));
        asm("v_fma_mix_f32 %0, %1, %2, %0 op_sel:[1,0,0] op_sel_hi:[1,0,0]"
            : "+v"(a[2 * k + 1]) : "v"(u.i[k]), "v"(fl));
    }
}

template <bool LAYER1>
__global__ __launch_bounds__(256) void agg_kernel(const int* __restrict__ rowptr_end,
                                                  const int* __restrict__ col,
                                                  const float* __restrict__ dis,
                                                  const half_t* __restrict__ hin,
                                                  half_t* __restrict__ hout,
                                                  const float* __restrict__ bias, int n) {
    const int bid   = blockIdx.x;
    const int chunk = (bid >> 2) & 1;                 // XCD group {0-3}->0, {4-7}->1
    const int nb    = (bid >> 3) * 4 + (bid & 3);     // node-block within chunk
    const int node  = nb * 32 + (threadIdx.x >> 3);   // 32 nodes per block
    if (node >= n) return;
    const int lane8 = threadIdx.x & 7;                // f16x8 (16B) within 64-feat half

    const f16x8* hc = (const f16x8*)(hin + (size_t)chunk * n * 64);

    int beg = (node == 0) ? 0 : rowptr_end[node - 1];
    int end = rowptr_end[node];

    float one = 1.0f;
    float a[8] = {};
    acc_mix8(a, hc[(size_t)node * 8 + lane8], one);   // self term

    int deg = end - beg;
    if (deg > 0) {
        const int last = end - 1;
        int c[8];
        #pragma unroll
        for (int j = 0; j < 8; j++) c[j] = col[min(beg + j, last)];

        int ng = (deg + 7) >> 3;
        int e = beg;
        for (int g = 0; g < ng; g++) {
            // issue the 8 long-latency gathers first (128B contiguous each)
            f16x8 v[8];
            #pragma unroll
            for (int j = 0; j < 8; j++) v[j] = hc[(size_t)c[j] * 8 + lane8];

            int enext = e + 8;
            if (g + 1 < ng) {
                // prefetch next col batch while gathers are in flight
                #pragma unroll
                for (int j = 0; j < 8; j++) c[j] = col[min(enext + j, last)];
                #pragma unroll
                for (int j = 0; j < 8; j++) acc_mix8(a, v[j], one);
            } else {
                int rem = end - e;   // 1..8 valid edges in the final group
                #pragma unroll
                for (int j = 0; j < 8; j++) {
                    float fl = (j < rem) ? 1.0f : 0.0f;
                    acc_mix8(a, v[j], fl);
                }
            }
            e = enext;
        }
    }

    float di = dis[node];
    if (LAYER1) {
        const float4 b0 = ((const float4*)bias)[chunk * 16 + lane8 * 2];
        const float4 b1 = ((const float4*)bias)[chunk * 16 + lane8 * 2 + 1];
        float bb[8] = { b0.x, b0.y, b0.z, b0.w, b1.x, b1.y, b1.z, b1.w };
        #pragma unroll
        for (int k = 0; k < 8; k++) {
            float t = a[k] * di + bb[k];
            a[k] = (t > 0.f ? t : 0.f) * di;
        }
    } else {
        #pragma unroll
        for (int k = 0; k < 8; k++) a[k] *= di;
    }
    f16x8 o = { (half_t)a[0], (half_t)a[1], (half_t)a[2], (half_t)a[3],
                (half_t)a[4], (half_t)a[5], (half_t)a[6], (half_t)a[7] };
    f16x8* outp = ((f16x8*)(hout + (size_t)chunk * n * 64)) + (size_t)node * 8 + lane8;
    if (LAYER1) *outp = o;
    else        __builtin_nontemporal_store(o, outp);   // gemm2 reads sequentially
}

extern "C" void kernel_launch(void* const* d_in, const int* in_sizes, int n_in,
                              void* d_out, int out_size, void* d_ws, size_t ws_size,
                              hipStream_t stream) {
    const float* x    = (const float*)d_in[0];
    const int*   ei   = (const int*)d_in[1];
    const float* W1   = (const float*)d_in[2];
    const float* b1   = (const float*)d_in[3];
    const float* Wmu  = (const float*)d_in[4];
    const float* bmu  = (const float*)d_in[5];
    const float* Wvar = (const float*)d_in[6];
    const float* bvar = (const float*)d_in[7];

    const int n = in_sizes[0] / 256;     // 100000
    const int E = in_sizes[1] / 2;       // 1600000
    const int* src = ei;
    const int* dst = ei + E;

    const int NB      = (n + 255) >> NB_SHIFT;       // 391
    const int nblocks = (E + CHUNK - 1) / CHUNK;     // 196
    const int flat    = NB * nblocks;
    const int nb_scan = (flat + 1023) / 1024;        // 75 (<= 1024)

    char* ws = (char*)d_ws;
    size_t off = 0;
    auto alloc = [&](size_t bytes) { void* p = ws + off; off = (off + bytes + 255) & ~(size_t)255; return p; };
    float*  dis     = (float*) alloc((size_t)n * 4);
    int*    rowptr  = (int*)   alloc((size_t)n * 4);
    int*    counts  = (int*)   alloc((size_t)flat * 4);
    int*    offsets = (int*)   alloc((size_t)flat * 4);
    int*    bsum    = (int*)   alloc((size_t)nb_scan * 4 + 256);
    int2*   binned  = (int2*)  alloc((size_t)E * 8);
    int*    col     = (int*)   alloc((size_t)E * 4);
    half_t* W1T     = (half_t*)alloc((size_t)256 * HID * 2);
    half_t* WcatT   = (half_t*)alloc((size_t)HID * HID * 2);
    half_t* hs      = (half_t*)alloc((size_t)n * HID * 2);  // gemm1 out, [2][n][64]
    half_t* h1s     = (half_t*)alloc((size_t)n * HID * 2);  // relu out, [2][n][64]
    half_t* agg2    = hs;                                   // alias: hs dead after agg1

    float* out_mu  = (float*)d_out;
    float* out_sig = (float*)d_out + (size_t)n * DOUT;

    // CSR build (scan3 folded; binscatter reuses counts for its local scan)
    bincount_kernel<<<nblocks, 256, 0, stream>>>(dst, counts, E, nblocks, NB);
    scan1_kernel<<<nb_scan, 256, 0, stream>>>(counts, offsets, bsum, flat);
    scan2_kernel<<<1, 1024, 0, stream>>>(bsum, nb_scan);
    binscatter_kernel<<<nblocks, 1024, 0, stream>>>(src, dst, counts, offsets, bsum, binned, E, nblocks, NB);
    csrbuild_kernel<<<NB, 256, 0, stream>>>(binned, offsets, bsum, rowptr, col, dis, E, nblocks, NB, n);

    // weights (merged)
    wprep_kernel<<<(256 * HID + HID * HID) / 256, 256, 0, stream>>>(W1, Wmu, Wvar, W1T, WcatT);

    // dense + sparse pipeline
    // agg grid: groups of 8 blocks = {4 node-blocks x chunk0, 4 x chunk1},
    // 32 nodes per block -> each group covers 128 nodes per chunk.
    const int aggGrid = ((n + 127) / 128) * 8;
    gemm1_mfma<<<(n + 63) / 64, 256, 0, stream>>>(x, W1T, dis, hs, n);
    agg_kernel<true><<<aggGrid, 256, 0, stream>>>(rowptr, col, dis, hs, h1s, b1, n);
    agg_kernel<false><<<aggGrid, 256, 0, stream>>>(rowptr, col, dis, h1s, agg2, nullptr, n);
    gemm2_mfma<<<(n + 63) / 64, 256, 0, stream>>>(agg2, WcatT, bmu, bvar, out_mu, out_sig, n);
}